// Round 3
// baseline (645.257 us; speedup 1.0000x reference)
//
#include <hip/hip_runtime.h>

#define SEQ 4096
#define NT  256
#define NA  64
#define NCKPT 32          // res checkpoints, every 128 steps
#define LOG2E 1.4426950408889634f

__device__ __forceinline__ float rdlanef(float v, int l) {
    return __int_as_float(__builtin_amdgcn_readlane(__float_as_int(v), l));
}

// ---------------------------------------------------------------------------
// k_prep: algo-independent probe-matrix precompute.
//   Tbuf[blk][j][i] = (LOG2E/diff[c_{64blk+j+1}]) * tm[c_{64blk+i}][c_{64blk+j+1}]
// Layout is lane-major (j = chain lane) so k_chain loads 16 coalesced float4
// per block instead of 64 readlane->scattered-load chains on the serial wave.
// ---------------------------------------------------------------------------
__global__ __launch_bounds__(256) void k_prep(
    const int* __restrict__ lx, const float* __restrict__ tm,
    const float* __restrict__ diff, float* __restrict__ Tbuf)
{
    const int t   = threadIdx.x;
    const int blk = blockIdx.x >> 2;
    const int sub = blockIdx.x & 3;
    const int j   = t & 63;
    const int i0  = (sub * 4 + (t >> 6)) * 4;

    int cjidx = 64 * blk + j + 1;
    if (cjidx > SEQ - 1) cjidx = SEQ - 1;
    const int   cj = lx[cjidx];
    const float kj = LOG2E / diff[cj];
    const float* src = tm + cj;
    float4 v;
    v.x = kj * src[lx[64 * blk + i0 + 0] * NT];
    v.y = kj * src[lx[64 * blk + i0 + 1] * NT];
    v.z = kj * src[lx[64 * blk + i0 + 2] * NT];
    v.w = kj * src[lx[64 * blk + i0 + 3] * NT];
    *(float4*)(Tbuf + ((blk * 64 + j) << 6) + i0) = v;
}

// ---------------------------------------------------------------------------
// Kernel 1: exact full-state chain, one wave per algo.
// v4: everything fused into the unrolled 64-step serial loop so off-chain work
// (res update, pf-ring refill, next-block T prefetch) issues inside the
// sigmoid chain's stall cycles. Chain per step: mul,fma,readlane,exp2,add,
// rcp,fma (~44 cy latency); fused issue ~38 cy < latency -> block ~= chain.
// T double-buffered via ping-pong macro (all register indices compile-time).
// ---------------------------------------------------------------------------
__global__ __launch_bounds__(64, 1) void k_chain(
    const int* __restrict__ lx, const float* __restrict__ tm,
    const float* __restrict__ diff, const float* __restrict__ eff_p,
    const float* __restrict__ mem_p, const float* __restrict__ boost_p,
    const float* __restrict__ Tbuf,
    float* __restrict__ gbuf, float* __restrict__ ckpt)
{
    __shared__ int   s_lx[SEQ + 16];
    __shared__ float s_kd[NT];
    __shared__ float s_res[NT];
    const int lane = threadIdx.x;
    const int a = blockIdx.x;

    for (int i = lane; i < SEQ; i += 64) s_lx[i] = lx[i];
    if (lane < 16) s_lx[SEQ + lane] = lx[SEQ - 1];
#pragma unroll
    for (int q = 0; q < 4; ++q)
        s_kd[4 * lane + q] = LOG2E / diff[4 * lane + q];
    __syncthreads();

    const float eff   = eff_p[a];
    const float mem   = mem_p[a];
    const float boost = boost_p[a];
    const float A  = eff + boost;
    const float Bc = -2.0f * boost;

    float4 res = make_float4(0.0f, 0.0f, 0.0f, 0.0f);
    float g = eff;            // g_0  (sig_{-1} = 0)
    float garr = g;
    float D = 0.0f;           // k*res_{-1}[c] = 0
    float TC[64], TN[64];
    float4 pf[8];
    int vrow2 = s_lx[8 + lane];           // refill rows: readlane(vrow2,j)=row B+8+j
#pragma unroll
    for (int d = 0; d < 8; ++d)
        pf[d] = *(const float4*)(tm + s_lx[d] * NT + 4 * lane);
#pragma unroll
    for (int i4 = 0; i4 < 64; i4 += 4)
        *(float4*)&TC[i4] = *(const float4*)(Tbuf + (lane << 6) + i4);

#define CHAIN_BLOCK(B, TCarr, TNarr)                                          \
  {                                                                           \
    int nb = ((B) >> 6) + 1; if (nb > 63) nb = 63;                            \
    const float* tnp = Tbuf + ((nb * 64 + lane) << 6);                        \
    _Pragma("unroll")                                                         \
    for (int j = 0; j < 64; ++j) {                                            \
      garr = (lane == j) ? g : garr;        /* capture g_{B+j} */             \
      const float tg = TCarr[j] * g;                                          \
      D = fmaf(mem, D, tg);                                                   \
      const float pb = rdlanef(D, j);                                         \
      const float qq = __builtin_amdgcn_rcpf(                                 \
                           __builtin_amdgcn_exp2f(pb) + 1.0f);                \
      const float4 row = pf[j & 7];         /* res update (off-chain) */      \
      res.x = fmaf(g, row.x, mem * res.x);                                    \
      res.y = fmaf(g, row.y, mem * res.y);                                    \
      res.z = fmaf(g, row.z, mem * res.z);                                    \
      res.w = fmaf(g, row.w, mem * res.w);                                    \
      const int rr = __builtin_amdgcn_readlane(vrow2, j);                     \
      pf[j & 7] = *(const float4*)(tm + rr * NT + 4 * lane);                  \
      if ((j & 3) == 0)                     /* next-block T prefetch */       \
        *(float4*)&TNarr[j] = *(const float4*)(tnp + j);                      \
      g = fmaf(Bc, qq, A);                                                    \
    }                                                                         \
    gbuf[a * SEQ + (B) + lane] = garr;                                        \
    if (((((B) >> 6)) & 1) == 1)                                              \
      *(float4*)(ckpt + (a * NCKPT + ((B) >> 7)) * NT + 4 * lane) = res;      \
    if ((B) + 64 < SEQ) {                                                     \
      __syncthreads();                                                        \
      *(float4*)&s_res[4 * lane] = res;                                      \
      __syncthreads();                                                        \
      const int vcoln = s_lx[(B) + 65 + lane];                                \
      D = s_kd[vcoln] * s_res[vcoln];                                         \
      vrow2 = s_lx[(B) + 72 + lane];                                          \
    }                                                                         \
  }

    for (int BB = 0; BB < SEQ; BB += 128) {
        CHAIN_BLOCK(BB, TC, TN)
        CHAIN_BLOCK(BB + 64, TN, TC)
    }
#undef CHAIN_BLOCK
}

// ---------------------------------------------------------------------------
// Kernel 2: regenerate sig for all (a, col, t) from g + checkpoints.
// v3: occupancy-focused. 128-thread blocks (2 independent waves sharing
// s_lx/s_g, each owning one 64-column group), chunk = 128 steps (NCKPT=32),
// 16x68 LDS tile slices (~9.8 KB/block -> 16 blocks/CU = 32 waves/CU, 4x the
// previous residency). Bank patterns on tile write/read are 2-way (free).
// ---------------------------------------------------------------------------
__global__ __launch_bounds__(128) void k_out(
    const int* __restrict__ lx, const float* __restrict__ tm,
    const float* __restrict__ diff, const float* __restrict__ mem_p,
    const float* __restrict__ gbuf, const float* __restrict__ ckpt,
    float* __restrict__ out)
{
    __shared__ int   s_lx[128 + 16];
    __shared__ float s_g[128];
    __shared__ float s_tile[2][16 * 68];

    const int tid  = threadIdx.x;
    const int lane = tid & 63;
    const int w    = tid >> 6;
    const int b = blockIdx.x;
    const int a     = b >> 6;
    const int cgp   = (b >> 5) & 1;
    const int chunk = b & 31;
    const int t0 = chunk << 7;
    const int cg = cgp * 2 + w;

    s_lx[tid] = lx[t0 + tid];
    s_g[tid]  = gbuf[a * SEQ + t0 + tid];
    if (tid < 16) s_lx[128 + tid] = lx[t0 + 127];
    __syncthreads();

    const int c = (cg << 6) + lane;
    const float memv = mem_p[a];
    const float kc = LOG2E / diff[c];
    float res = (chunk == 0) ? 0.0f
                             : ckpt[(a * NCKPT + chunk - 1) * NT + c];

    float pf[16];
#pragma unroll
    for (int d = 0; d < 16; ++d) pf[d] = tm[s_lx[d] * NT + c];

    float* tile = &s_tile[w][0];
    const long rowbase = (long)(a * NT + (cg << 6)) * (SEQ + 1);

    for (int jb = 0; jb < 128; jb += 64) {
        const float vg  = s_g[jb + lane];
        const int   vpf = s_lx[jb + 16 + lane];
        for (int sl = 0; sl < 4; ++sl) {
#pragma unroll
            for (int q = 0; q < 16; ++q) {
                const int j2 = sl * 16 + q;
                const int i = jb + j2;
                const float gi  = rdlanef(vg, j2);
                const float tmv = pf[i & 15];
                res = fmaf(memv, res, tmv * gi);
                const float qq = __builtin_amdgcn_rcpf(
                                     __builtin_amdgcn_exp2f(res * kc) + 1.0f);
                tile[q * 68 + lane] = fmaf(-2.0f, qq, 1.0f);
                const int rowi = __builtin_amdgcn_readlane(vpf, j2);
                pf[i & 15] = tm[rowi * NT + c];
            }
            __syncthreads();
            const int tb = t0 + jb + sl * 16 + 1;
            const int csub = lane >> 4;
            const int tsub = lane & 15;
#pragma unroll
            for (int rr = 0; rr < 16; ++rr) {
                out[rowbase + (long)(rr * 4 + csub) * (SEQ + 1) + tb + tsub] =
                    tile[tsub * 68 + rr * 4 + csub];
            }
            __syncthreads();
        }
    }
    if (chunk == 0) out[rowbase + (long)lane * (SEQ + 1)] = 0.0f;
}

extern "C" void kernel_launch(void* const* d_in, const int* in_sizes, int n_in,
                              void* d_out, int out_size, void* d_ws, size_t ws_size,
                              hipStream_t stream)
{
    const int*   lx    = (const int*)d_in[0];
    const float* tm    = (const float*)d_in[1];
    const float* diff  = (const float*)d_in[2];
    const float* eff   = (const float*)d_in[3];
    const float* memp  = (const float*)d_in[4];
    const float* boost = (const float*)d_in[5];
    float* gbuf = (float*)d_ws;                          // 64*4096*4   = 1 MB
    float* ckpt = gbuf + NA * SEQ;                       // 64*32*256*4 = 2 MB
    float* Tbuf = ckpt + NA * NCKPT * NT;                // 64*64*64*4  = 1 MB
    float* out  = (float*)d_out;

    k_prep<<<256, 256, 0, stream>>>(lx, tm, diff, Tbuf);
    k_chain<<<NA, 64, 0, stream>>>(lx, tm, diff, eff, memp, boost, Tbuf, gbuf, ckpt);
    k_out<<<NA * 2 * 32, 128, 0, stream>>>(lx, tm, diff, memp, gbuf, ckpt, out);
}

// Round 4
// 483.639 us; speedup vs baseline: 1.3342x; 1.3342x over previous
//
#include <hip/hip_runtime.h>

#define SEQ 4096
#define NT  256
#define NA  64
#define NCKPT 16          // res checkpoints: ckpt[m-1] = res after step 256m-1
#define LOG2E 1.4426950408889634f

__device__ __forceinline__ float rdlanef(float v, int l) {
    return __int_as_float(__builtin_amdgcn_readlane(__float_as_int(v), l));
}

// ---------------------------------------------------------------------------
// k_prep: same-block probe matrix, coalesced layout.
//   Tbuf[blk][q][j][s] = k_j * tm[c_{64blk+4q+s}][c_{64blk+j+1}]   (q=i>>2)
// so k_chain wave0 loads T[4q..4q+3] with one 1KB-coalesced float4/lane.
// ---------------------------------------------------------------------------
__global__ __launch_bounds__(256) void k_prep(
    const int* __restrict__ lx, const float* __restrict__ tm,
    const float* __restrict__ diff, float* __restrict__ Tbuf)
{
    const int t   = threadIdx.x;
    const int blk = blockIdx.x >> 2;
    const int sub = blockIdx.x & 3;
    const int j   = t & 63;
    const int i0  = (sub * 4 + (t >> 6)) * 4;

    int cjidx = 64 * blk + j + 1;
    if (cjidx > SEQ - 1) cjidx = SEQ - 1;
    const int   cj = lx[cjidx];
    const float kj = LOG2E / diff[cj];
    const float* src = tm + cj;
    float4 v;
    v.x = kj * src[lx[64 * blk + i0 + 0] * NT];
    v.y = kj * src[lx[64 * blk + i0 + 1] * NT];
    v.z = kj * src[lx[64 * blk + i0 + 2] * NT];
    v.w = kj * src[lx[64 * blk + i0 + 3] * NT];
    *(float4*)(Tbuf + ((blk * 16 + (i0 >> 2)) << 8) + 4 * j) = v;
}

// ---------------------------------------------------------------------------
// k_prep2: cross-block probe matrix (rows of block n, probe cols of block n+1)
//   Vbuf[n][q][j][s] = k'_j * tm[c_{64n+4q+s}][c_{64(n+1)+j+1}],  n = 0..62
// Feeds the fused vA accumulator that bridges the one-block res lag.
// ---------------------------------------------------------------------------
__global__ __launch_bounds__(256) void k_prep2(
    const int* __restrict__ lx, const float* __restrict__ tm,
    const float* __restrict__ diff, float* __restrict__ Vbuf)
{
    const int t   = threadIdx.x;
    const int n   = blockIdx.x >> 2;
    const int sub = blockIdx.x & 3;
    const int j   = t & 63;
    const int i0  = (sub * 4 + (t >> 6)) * 4;

    int cjidx = 64 * (n + 1) + j + 1;
    if (cjidx > SEQ - 1) cjidx = SEQ - 1;
    const int   cj = lx[cjidx];
    const float kj = LOG2E / diff[cj];
    const float* src = tm + cj;
    float4 v;
    v.x = kj * src[lx[64 * n + i0 + 0] * NT];
    v.y = kj * src[lx[64 * n + i0 + 1] * NT];
    v.z = kj * src[lx[64 * n + i0 + 2] * NT];
    v.w = kj * src[lx[64 * n + i0 + 3] * NT];
    *(float4*)(Vbuf + ((n * 16 + (i0 >> 2)) << 8) + 4 * j) = v;
}

// ---------------------------------------------------------------------------
// Kernel 1 v5: producer-consumer wave specialization. Block = 2 waves.
//   wave 0: pure sigmoid chain. Per step: garr capture, D & vA fma, readlane,
//           exp2, +1, rcp, fma  -- NO memory ops in the 64-step loop.
//           Per block: load T,V (coalesced, register-resident), D-init from
//           s_res (2 blocks behind) + vA (bridges the gap), publish garr.
//   wave 1: full res state, one block behind, exact reference nesting.
//           Publishes s_res, stores gbuf + ckpt.
// All cross-wave traffic crosses the one barrier per slot; ping-pong parity:
// wave0 writes s_g[n&1], reads s_res[n&1]; wave1 writes s_res[(n-1)&1],
// reads s_g[(n-1)&1] -- disjoint buffers within any slot.
// ---------------------------------------------------------------------------
__global__ __launch_bounds__(128, 1) void k_chain(
    const int* __restrict__ lx, const float* __restrict__ tm,
    const float* __restrict__ diff, const float* __restrict__ eff_p,
    const float* __restrict__ mem_p, const float* __restrict__ boost_p,
    const float* __restrict__ Tbuf, const float* __restrict__ Vbuf,
    float* __restrict__ gbuf, float* __restrict__ ckpt)
{
    __shared__ int   s_lx[SEQ + 16];
    __shared__ float s_kd[NT];
    __shared__ float s_res[2][NT];
    __shared__ float s_g[2][64];

    const int tid  = threadIdx.x;
    const int lane = tid & 63;
    const int w    = tid >> 6;
    const int a    = blockIdx.x;

    for (int i = tid; i < SEQ; i += 128) s_lx[i] = lx[i];
    if (tid < 16) s_lx[SEQ + tid] = lx[SEQ - 1];
    s_kd[tid]       = LOG2E / diff[tid];
    s_kd[tid + 128] = LOG2E / diff[tid + 128];
    s_res[0][tid] = 0.0f; s_res[0][tid + 128] = 0.0f;
    s_res[1][tid] = 0.0f; s_res[1][tid + 128] = 0.0f;
    __syncthreads();

    const float eff   = eff_p[a];
    const float mem   = mem_p[a];
    const float boost = boost_p[a];
    const float A  = eff + boost;
    const float Bc = -2.0f * boost;
    float m64 = mem;
#pragma unroll
    for (int k = 0; k < 6; ++k) m64 *= m64;     // mem^64

    // wave-0 state
    float T[64], V[64];
    float D = 0.0f, vA = 0.0f, g = eff, garr = eff;
    // wave-1 state
    float4 res = make_float4(0.0f, 0.0f, 0.0f, 0.0f);
    float4 pf[8];

    for (int n = 0; n <= 64; ++n) {
        if (w == 0 && n < 64) {
            // ---- per-block T/V loads (coalesced, register-resident) ----
            const float* tb = Tbuf + ((n * 16) << 8) + 4 * lane;
            const float* vb = Vbuf + ((n * 16) << 8) + 4 * lane;
#pragma unroll
            for (int q = 0; q < 16; ++q) {
                *(float4*)&T[4 * q] = *(const float4*)(tb + (q << 8));
                if (n < 63)
                    *(float4*)&V[4 * q] = *(const float4*)(vb + (q << 8));
            }
            // ---- D-init: k'*(mem^64 * res_{thru n-2}[c'] ) + vA_{n-1} ----
            const int   vcol = s_lx[64 * n + 1 + lane];
            const float kp   = s_kd[vcol];
            const float Rv   = s_res[n & 1][vcol];
            D  = fmaf(kp * m64, Rv, vA);
            vA = 0.0f;
            // ---- pure-register serial chain, 64 steps ----
#pragma unroll
            for (int j = 0; j < 64; ++j) {
                garr = (lane == j) ? g : garr;
                D  = fmaf(T[j], g, mem * D);
                vA = fmaf(V[j], g, mem * vA);
                const float pb = rdlanef(D, j);
                const float q2 = __builtin_amdgcn_rcpf(
                                     __builtin_amdgcn_exp2f(pb) + 1.0f);
                g = fmaf(Bc, q2, A);
            }
            s_g[n & 1][lane] = garr;
        }
        if (w == 1 && n > 0) {
            const int bm1 = n - 1;
            const int S1  = bm1 << 6;
            const float vg = s_g[bm1 & 1][lane];
            gbuf[a * SEQ + S1 + lane] = vg;
            const int vrow = s_lx[S1 + lane];
#pragma unroll
            for (int d = 0; d < 8; ++d) {
                const int rr = __builtin_amdgcn_readlane(vrow, d);
                pf[d] = *(const float4*)(tm + rr * NT + 4 * lane);
            }
#pragma unroll
            for (int i = 0; i < 64; ++i) {
                const float gi = rdlanef(vg, i);
                const float4 row = pf[i & 7];
                res.x = fmaf(gi, row.x, mem * res.x);
                res.y = fmaf(gi, row.y, mem * res.y);
                res.z = fmaf(gi, row.z, mem * res.z);
                res.w = fmaf(gi, row.w, mem * res.w);
                if (i < 56) {
                    const int rr = __builtin_amdgcn_readlane(vrow, i + 8);
                    pf[i & 7] = *(const float4*)(tm + rr * NT + 4 * lane);
                }
            }
            *(float4*)&s_res[bm1 & 1][4 * lane] = res;
            if ((bm1 & 3) == 3)     // res after step 256m-1 -> ckpt[m-1]
                *(float4*)(ckpt + (a * NCKPT + (bm1 >> 2)) * NT + 4 * lane) = res;
        }
        __syncthreads();
    }
}

// ---------------------------------------------------------------------------
// Kernel 2 v4: emit-then-update, aligned stores. Chunk m emits
// out[tau] = sig_{tau-1} for tau in [256m, 256m+255] (store base 256B-aligned;
// tau=0 emits sigma'(0)=0 naturally). res init = ckpt[m-1] = res_{256m-1}.
// tau=4096 from chunk 15's final register res. 64x65 LDS tile transpose,
// 256B coalesced stores along t.
// ---------------------------------------------------------------------------
__global__ __launch_bounds__(64) void k_out(
    const int* __restrict__ lx, const float* __restrict__ tm,
    const float* __restrict__ diff, const float* __restrict__ mem_p,
    const float* __restrict__ gbuf, const float* __restrict__ ckpt,
    float* __restrict__ out)
{
    __shared__ int   s_lx[256 + 16];
    __shared__ float s_g[256];
    __shared__ float s_tile[64 * 65];

    const int lane = threadIdx.x;
    const int b = blockIdx.x;
    const int a     = b >> 6;
    const int cg    = (b >> 4) & 3;
    const int chunk = b & 15;
    const int t0 = chunk << 8;

    for (int i = lane; i < 256; i += 64) {
        s_lx[i] = lx[t0 + i];
        s_g[i]  = gbuf[a * SEQ + t0 + i];
    }
    if (lane < 16) s_lx[256 + lane] = lx[t0 + 255];
    __syncthreads();

    const int c = (cg << 6) + lane;
    const float memv = mem_p[a];
    const float kc = LOG2E / diff[c];
    float res = (chunk == 0) ? 0.0f
                             : ckpt[(a * NCKPT + chunk - 1) * NT + c];

    float pf[16];
#pragma unroll
    for (int d = 0; d < 16; ++d) pf[d] = tm[s_lx[d] * NT + c];

    const long rowbase = (long)(a * NT + (cg << 6)) * (SEQ + 1);
    for (int jb = 0; jb < 256; jb += 64) {
        const float vg  = s_g[jb + lane];
        const int   vpf = s_lx[jb + 16 + lane];
        for (int j0 = 0; j0 < 64; j0 += 8) {
#pragma unroll
            for (int ji = 0; ji < 8; ++ji) {
                const int j2 = j0 + ji;
                const int i  = jb + j2;
                // emit sig_{t0+i-1} from current res
                const float q = __builtin_amdgcn_rcpf(
                                    __builtin_amdgcn_exp2f(res * kc) + 1.0f);
                s_tile[j2 * 65 + lane] = fmaf(-2.0f, q, 1.0f);
                // update step t0+i
                const float gi  = rdlanef(vg, j2);
                const float tmv = pf[i & 15];
                res = fmaf(memv, res, tmv * gi);
                const int rowi = __builtin_amdgcn_readlane(vpf, j2);
                pf[i & 15] = tm[rowi * NT + c];
            }
        }
        __syncthreads();
        const int tbase = t0 + jb;          // 256B-aligned store base
#pragma unroll 8
        for (int r = 0; r < 64; ++r) {
            out[rowbase + (long)r * (SEQ + 1) + tbase + lane] =
                s_tile[lane * 65 + r];
        }
        __syncthreads();
    }
    if (chunk == 15) {   // tau = 4096 from final res
        const float q = __builtin_amdgcn_rcpf(
                            __builtin_amdgcn_exp2f(res * kc) + 1.0f);
        out[rowbase + (long)lane * (SEQ + 1) + SEQ] = fmaf(-2.0f, q, 1.0f);
    }
}

extern "C" void kernel_launch(void* const* d_in, const int* in_sizes, int n_in,
                              void* d_out, int out_size, void* d_ws, size_t ws_size,
                              hipStream_t stream)
{
    const int*   lx    = (const int*)d_in[0];
    const float* tm    = (const float*)d_in[1];
    const float* diff  = (const float*)d_in[2];
    const float* eff   = (const float*)d_in[3];
    const float* memp  = (const float*)d_in[4];
    const float* boost = (const float*)d_in[5];
    float* gbuf = (float*)d_ws;                          // 64*4096*4       = 1 MB
    float* ckpt = gbuf + NA * SEQ;                       // 64*16*256*4     = 1 MB
    float* Tbuf = ckpt + NA * NCKPT * NT;                // 64*64*64*4      = 1 MB
    float* Vbuf = Tbuf + 64 * 64 * 64;                   // 63*64*64*4     ~= 1 MB
    float* out  = (float*)d_out;

    k_prep <<<256, 256, 0, stream>>>(lx, tm, diff, Tbuf);
    k_prep2<<<252, 256, 0, stream>>>(lx, tm, diff, Vbuf);
    k_chain<<<NA, 128, 0, stream>>>(lx, tm, diff, eff, memp, boost,
                                    Tbuf, Vbuf, gbuf, ckpt);
    k_out  <<<NA * 4 * NCKPT, 64, 0, stream>>>(lx, tm, diff, memp, gbuf, ckpt, out);
}